// Round 13
// baseline (232.528 us; speedup 1.0000x reference)
//
#include <hip/hip_runtime.h>

typedef unsigned short u16;
typedef __attribute__((ext_vector_type(8))) short short8;   // 8 bf16 (guide-verified MFMA frag type)
typedef __attribute__((ext_vector_type(4))) float f32x4;

// Workspace layout (u16 element offsets). Total 13,390,848 u16 = 26.8 MB.
#define XCB_OFF  0          // xc  channels-last bf16 [2][16^4][64] = 8,388,608
#define Y1B_OFF  8388608    // Y1  channels-last bf16 [2][16^4][32] = 4,194,304
#define W1P_OFF  12582912   // w1 prepacked [tap81][chunk2][half2][lane64][8] = 165,888
#define W2P_OFF  12748800   // w2 prepacked [tap81][half2][lane64][8]         =  82,944
#define W3P_OFF  12831744   // w3 prepacked [chunk2][half2][lane64][8]        =   2,048
#define UPWP_OFF 12833792   // up_w prepacked [tap16][chunk2][half2][lane64][8] = 32,768
#define X1T_OFF  12866560   // x1 channels-last bf16 [2][4096][64]            = 524,288

__device__ __forceinline__ u16 f2bf(float v) {   // RNE fp32 -> bf16 bits
    unsigned u = __builtin_bit_cast(unsigned, v);
    u += 0x7FFFu + ((u >> 16) & 1u);
    return (u16)(u >> 16);
}

__device__ __forceinline__ f32x4 MFMA(short8 a, short8 b, f32x4 c) {
    return __builtin_amdgcn_mfma_f32_16x16x32_bf16(a, b, c, 0, 0, 0);
}

// bid decode for conv kernels: grid 1024 = [b2][tsub2][d16][hB2][xcd8],
// xcd = bid&7 pinned to a t-pair (L2 locality). Each block = 8 h-rows.
__device__ __forceinline__ void decode_bid(int bid, int& b, int& t, int& d, int& h0) {
    int xcd = bid & 7, loc = bid >> 3;
    int hB = loc & 1;
    d = (loc >> 1) & 15;
    int tsub = (loc >> 5) & 1;
    b = loc >> 6;
    t = xcd * 2 + tsub;
    h0 = hB * 8;
}

// ---------------------------------------------------------------------------
// setup: fused (prepack weights | xc_copy | x1_tr) — all independent writes,
// branch by block range.
// ---------------------------------------------------------------------------
__global__ __launch_bounds__(256) void setup(const float* __restrict__ w1,
                                             const float* __restrict__ w2,
                                             const float* __restrict__ w3,
                                             const float* __restrict__ upw,
                                             const float* __restrict__ x1,
                                             const float* __restrict__ x2,
                                             u16* __restrict__ ws) {
    __shared__ u16 lds[256 * 66];
    int bid = blockIdx.x;
    int tid = threadIdx.x;
    if (bid < 1108) {
        // ---- prepack into MFMA A-frag order: a[lane][j] = A[m=lane&15][k=(lane>>4)*8+j]
        int idx = bid * 256 + tid;
        if (idx < 165888) {
            int j = idx & 7, lane = (idx >> 3) & 63, rest = idx >> 9;
            int half = rest & 1, chunk = (rest >> 1) & 1, tap = rest >> 2;
            int co = half * 16 + (lane & 15), ci = chunk * 32 + (lane >> 4) * 8 + j;
            ws[W1P_OFF + idx] = f2bf(w1[(co * 64 + ci) * 81 + tap]);
        } else if (idx < 165888 + 82944) {
            int i2 = idx - 165888;
            int j = i2 & 7, lane = (i2 >> 3) & 63, rest = i2 >> 9;
            int half = rest & 1, tap = rest >> 1;
            int co = half * 16 + (lane & 15), ci = (lane >> 4) * 8 + j;
            ws[W2P_OFF + i2] = f2bf(w2[(co * 32 + ci) * 81 + tap]);
        } else if (idx < 165888 + 82944 + 2048) {
            int i3 = idx - (165888 + 82944);
            int j = i3 & 7, lane = (i3 >> 3) & 63, rest = i3 >> 9;   // chunk*2+half
            int half = rest & 1, chunk = rest >> 1;
            int co = half * 16 + (lane & 15), ci = chunk * 32 + (lane >> 4) * 8 + j;
            ws[W3P_OFF + i3] = f2bf(w3[co * 64 + ci]);
        } else if (idx < 250880 + 32768) {
            int i4 = idx - 250880;                        // [tap][chunk][half][lane][8]
            int j = i4 & 7, lane = (i4 >> 3) & 63, rest = i4 >> 9;
            int half = rest & 1, chunk = (rest >> 1) & 1, tap = rest >> 2;
            int co = half * 16 + (lane & 15), ci = chunk * 32 + (lane >> 4) * 8 + j;
            ws[UPWP_OFF + i4] = f2bf(upw[(ci * 32 + co) * 16 + tap]);   // [Cin][Cout][taps]
        }
    } else if (bid < 1620) {
        // ---- xc_copy: x2 -> xcb channels 0..31 via padded-LDS transpose
        int lb = bid - 1108;
        int b = lb >> 8;
        int pos_base = (lb & 255) * 256;
        u16* xcb = ws + XCB_OFF;
        #pragma unroll
        for (int c = 0; c < 32; ++c) {
            lds[tid * 40 + c] = f2bf(x2[((b * 32 + c) << 16) + pos_base + tid]);
        }
        __syncthreads();
        #pragma unroll
        for (int k = 0; k < 4; ++k) {
            int f = k * 256 + tid;
            int u = f & 3, pos = f >> 2;
            uint4 v = *(const uint4*)(lds + pos * 40 + u * 8);
            *(uint4*)(xcb + (size_t)((b << 16) + pos_base + pos) * 64 + u * 8) = v;
        }
    } else {
        // ---- x1_tr: x1 -> x1t channels-last bf16 via padded-LDS transpose
        int lb = bid - 1620;                 // 32 blocks
        int b = lb >> 4;
        int pos_base = (lb & 15) * 256;
        u16* x1t = ws + X1T_OFF;
        #pragma unroll
        for (int c = 0; c < 64; ++c) {
            lds[tid * 66 + c] = f2bf(x1[((b * 64 + c) << 12) + pos_base + tid]);
        }
        __syncthreads();
        #pragma unroll
        for (int k = 0; k < 64; ++k) {
            int f = k * 256 + tid;
            int ci = f & 63, pos = f >> 6;
            x1t[(size_t)((b << 12) + pos_base + pos) * 64 + ci] = lds[pos * 66 + ci];
        }
    }
}

// ---------------------------------------------------------------------------
// xc_up_mfma: tconv4d(k2,s2) as 32 per-(b,tap) GEMMs [4096 ipos x 32 co, K=64].
// ---------------------------------------------------------------------------
__global__ __launch_bounds__(256) void xc_up_mfma(const u16* __restrict__ x1t,
                                                  const u16* __restrict__ upwp,
                                                  const float* __restrict__ up_b,
                                                  u16* __restrict__ xcb) {
    int tid = threadIdx.x;
    int wv = tid >> 6, lane = tid & 63;
    int q = lane >> 4, m = lane & 15;
    int wid = blockIdx.x * 4 + wv;               // [b2][tap16][j64]
    int j = wid & 63, tap = (wid >> 6) & 15, b = wid >> 10;

    f32x4 acc[4][2];
    {
        float4 bi0 = ((const float4*)up_b)[q];       // co = q*4+r
        float4 bi1 = ((const float4*)up_b)[4 + q];   // co = 16+q*4+r
        #pragma unroll
        for (int g = 0; g < 4; ++g) {
            acc[g][0] = (f32x4){bi0.x, bi0.y, bi0.z, bi0.w};
            acc[g][1] = (f32x4){bi1.x, bi1.y, bi1.z, bi1.w};
        }
    }

    const short8* wv8 = (const short8*)upwp;
    const u16* xb = x1t + (size_t)((b << 12) + (j << 6) + m) * 64;   // + (g*16)*64
    #pragma unroll
    for (int chunk = 0; chunk < 2; ++chunk) {
        short8 a0 = wv8[((tap * 2 + chunk) * 2 + 0) * 64 + lane];
        short8 a1 = wv8[((tap * 2 + chunk) * 2 + 1) * 64 + lane];
        #pragma unroll
        for (int g = 0; g < 4; ++g) {
            short8 bf = *(const short8*)(xb + (size_t)(g * 16) * 64 + chunk * 32 + q * 8);
            acc[g][0] = MFMA(a0, bf, acc[g][0]);
            acc[g][1] = MFMA(a1, bf, acc[g][1]);
        }
    }

    // epilogue: C/D col = ipos-local (lane&15), row = co-in-half = q*4+r.
    int it = j >> 3, id = j & 7;
    int pt = tap >> 3, pd = (tap >> 2) & 1, ph = (tap >> 1) & 1, pw = tap & 1;
    int oT = 2 * it + pt, oD = 2 * id + pd, oW = 2 * (m & 7) + pw;
    #pragma unroll
    for (int g = 0; g < 4; ++g) {
        int ih = g * 2 + (m >> 3);
        int opos = oT * 4096 + oD * 256 + (2 * ih + ph) * 16 + oW;
        u16* op = xcb + (size_t)((b << 16) + opos) * 64 + 32 + q * 4;
        #pragma unroll
        for (int half = 0; half < 2; ++half) {
            f32x4 v = acc[g][half];
            uint2 o;
            o.x = (unsigned)f2bf(v.x) | ((unsigned)f2bf(v.y) << 16);
            o.y = (unsigned)f2bf(v.z) | ((unsigned)f2bf(v.w) << 16);
            *(uint2*)(op + half * 16) = o;
        }
    }
}

// ---------------------------------------------------------------------------
// conv1: 3^4 conv, Cin=64 -> Cout=32, pad 1, +bias +ReLU -> Y1 (channels-last
// bf16). Block = 4 waves = (ci-chunk c) x (rowgroup rg), 8 h-rows x 32 co,
// grid 1024. BARRIER-FREE K-loop: B-fragments are contiguous 16B/lane in the
// channels-last xcb -> loaded DIRECTLY from global (L2 is XCD-local via the
// bid swizzle). No LDS staging, no per-plane __syncthreads (the r11/r12
// 2-barrier structure was the ~60% stall; cf. m97 plateau). Invalid planes
// skipped entirely (uniform branch). Only the final K-reduction uses LDS.
// ---------------------------------------------------------------------------
__global__ __launch_bounds__(256, 4) void conv1_mfma(const u16* __restrict__ xcb,
                                                     const u16* __restrict__ w1p,
                                                     const float* __restrict__ b1,
                                                     u16* __restrict__ y1b) {
    __shared__ f32x4 red[1024];                  // 16 KB K-reduction buffer
    int tid = threadIdx.x;
    int lane = tid & 63, wv = tid >> 6;
    int q = lane >> 4, m = lane & 15;
    int c = wv & 1, rg = wv >> 1;                // ci-chunk, rowgroup
    int b, t, d, h0;
    decode_bid(blockIdx.x, b, t, d, h0);
    int hbase = h0 + rg * 4 - 1;                 // input row of R[0]
    int coff = ((c << 2) | q) * 8;               // ci offset within pos record

    f32x4 acc[4][2];                             // [row i][co half]
    if (c == 0) {
        float4 bi0 = ((const float4*)b1)[q];
        float4 bi1 = ((const float4*)b1)[4 + q];
        #pragma unroll
        for (int i = 0; i < 4; ++i) {
            acc[i][0] = (f32x4){bi0.x, bi0.y, bi0.z, bi0.w};
            acc[i][1] = (f32x4){bi1.x, bi1.y, bi1.z, bi1.w};
        }
    } else {
        #pragma unroll
        for (int i = 0; i < 4; ++i) {
            acc[i][0] = (f32x4){0.f, 0.f, 0.f, 0.f};
            acc[i][1] = (f32x4){0.f, 0.f, 0.f, 0.f};
        }
    }
    const short8* w1v = (const short8*)w1p;

    for (int ktd = 0; ktd < 9; ++ktd) {
        int kt = ktd / 3, kd = ktd - kt * 3;
        int tt = t + kt - 1, dd = d + kd - 1;
        if (((unsigned)tt >= 16u) || ((unsigned)dd >= 16u)) continue;   // zero plane
        const u16* pb = xcb + (size_t)((b * 16 + tt) * 16 + dd) * 16384;
        #pragma unroll
        for (int kw = 0; kw < 3; ++kw) {
            int gw = kw - 1 + m;
            bool vw = (unsigned)gw < 16u;        // only m=0/kw=0, m=15/kw=2 invalid
            int lo = gw * 64 + coff;
            short8 R[6];
            #pragma unroll
            for (int r = 0; r < 6; ++r) {        // input rows hbase..hbase+5
                int gh = hbase + r;
                short8 v = {0, 0, 0, 0, 0, 0, 0, 0};
                if (vw && (unsigned)gh < 16u)
                    v = *(const short8*)(pb + gh * 1024 + lo);
                R[r] = v;
            }
            #pragma unroll
            for (int kh = 0; kh < 3; ++kh) {
                int tap = (ktd * 3 + kh) * 3 + kw;
                short8 a0 = w1v[((tap * 2 + c) * 2 + 0) * 64 + lane];
                short8 a1 = w1v[((tap * 2 + c) * 2 + 1) * 64 + lane];
                #pragma unroll
                for (int i = 0; i < 4; ++i) {
                    acc[i][0] = MFMA(a0, R[i + kh], acc[i][0]);
                    acc[i][1] = MFMA(a1, R[i + kh], acc[i][1]);
                }
            }
        }
    }

    // ---- K-reduction: chunk1 partials -> chunk0, via LDS ----
    if (c == 1) {
        #pragma unroll
        for (int i = 0; i < 4; ++i)
            #pragma unroll
            for (int half = 0; half < 2; ++half)
                red[((rg * 4 + i) * 2 + half) * 64 + lane] = acc[i][half];
    }
    __syncthreads();
    if (c == 0) {
        int obase = ((b * 16 + t) * 16 + d) * 256 + (h0 + rg * 4) * 16 + m;
        #pragma unroll
        for (int i = 0; i < 4; ++i) {
            int pos = obase + i * 16;
            #pragma unroll
            for (int half = 0; half < 2; ++half) {
                f32x4 v = acc[i][half];
                f32x4 w = red[((rg * 4 + i) * 2 + half) * 64 + lane];
                v.x += w.x; v.y += w.y; v.z += w.z; v.w += w.w;
                unsigned r0 = f2bf(fmaxf(v.x, 0.f)), r1 = f2bf(fmaxf(v.y, 0.f));
                unsigned r2 = f2bf(fmaxf(v.z, 0.f)), r3 = f2bf(fmaxf(v.w, 0.f));
                uint2 o;
                o.x = r0 | (r1 << 16);
                o.y = r2 | (r3 << 16);
                *(uint2*)(y1b + (size_t)pos * 32 + half * 16 + q * 4) = o;
            }
        }
    }
}

// ---------------------------------------------------------------------------
// conv2: 3^4 conv Cin=32->Cout=32 on Y1 + fused 1x1 skip (xc, Cin=64) + biases
// + final ReLU -> fp32 output [b][co][t][d][h][w]. Block = 4 waves =
// (co-half hf) x (rowgroup rg), grid 1024. Barrier-free, zero LDS: B-frags
// direct from global y1b (channels-last, 16B/lane contiguous).
// ---------------------------------------------------------------------------
__global__ __launch_bounds__(256, 4) void conv2_mfma(const u16* __restrict__ y1b,
                                                     const u16* __restrict__ xcb,
                                                     const u16* __restrict__ w2p,
                                                     const u16* __restrict__ w3p,
                                                     const float* __restrict__ b2,
                                                     const float* __restrict__ b3,
                                                     float* __restrict__ out) {
    int tid = threadIdx.x;
    int lane = tid & 63, wv = tid >> 6;
    int q = lane >> 4, m = lane & 15;
    int hf = wv & 1, rg = wv >> 1;               // co-half, rowgroup
    int b, t, d, h0;
    decode_bid(blockIdx.x, b, t, d, h0);
    int hbase = h0 + rg * 4 - 1;

    f32x4 acc[4];                                // [row i], this wave's co-half
    {
        float4 p0 = ((const float4*)b2)[hf * 4 + q];
        float4 s0 = ((const float4*)b3)[hf * 4 + q];
        #pragma unroll
        for (int i = 0; i < 4; ++i)
            acc[i] = (f32x4){p0.x + s0.x, p0.y + s0.y, p0.z + s0.z, p0.w + s0.w};
    }
    const short8* w2v = (const short8*)w2p;

    for (int ktd = 0; ktd < 9; ++ktd) {
        int kt = ktd / 3, kd = ktd - kt * 3;
        int tt = t + kt - 1, dd = d + kd - 1;
        if (((unsigned)tt >= 16u) || ((unsigned)dd >= 16u)) continue;
        const u16* pb = y1b + (size_t)((b * 16 + tt) * 16 + dd) * 8192;
        #pragma unroll
        for (int kw = 0; kw < 3; ++kw) {
            int gw = kw - 1 + m;
            bool vw = (unsigned)gw < 16u;
            int lo = gw * 32 + q * 8;
            short8 R[6];
            #pragma unroll
            for (int r = 0; r < 6; ++r) {
                int gh = hbase + r;
                short8 v = {0, 0, 0, 0, 0, 0, 0, 0};
                if (vw && (unsigned)gh < 16u)
                    v = *(const short8*)(pb + gh * 512 + lo);
                R[r] = v;
            }
            #pragma unroll
            for (int kh = 0; kh < 3; ++kh) {
                int tap = (ktd * 3 + kh) * 3 + kw;
                short8 a = w2v[(tap * 2 + hf) * 64 + lane];
                #pragma unroll
                for (int i = 0; i < 4; ++i) {
                    acc[i] = MFMA(a, R[i + kh], acc[i]);
                }
            }
        }
    }

    // ---- fused 1x1 skip conv from xc (Cin=64, 2 chunks), B direct from global
    const short8* w3v = (const short8*)w3p;
    int lpos0 = (t * 16 + d) * 256 + (h0 + rg * 4) * 16 + m;   // batch-local pos
    int gpos0 = (b << 16) + lpos0;                             // global pos (ws arrays)
    #pragma unroll
    for (int chunk = 0; chunk < 2; ++chunk) {
        short8 a = w3v[(chunk * 2 + hf) * 64 + lane];
        #pragma unroll
        for (int i = 0; i < 4; ++i) {
            short8 bf = *(const short8*)(xcb + (size_t)(gpos0 + i * 16) * 64 + ((chunk << 2) | q) * 8);
            acc[i] = MFMA(a, bf, acc[i]);
        }
    }

    // ---- epilogue: ReLU, fp32 store to [b][co][local_pos] ----
    #pragma unroll
    for (int i = 0; i < 4; ++i) {
        int lpos = lpos0 + i * 16;
        f32x4 v = acc[i];
        int co = hf * 16 + q * 4;
        float* op = out + (((size_t)(b * 32 + co)) << 16) + lpos;
        op[0ull << 16] = fmaxf(v.x, 0.f);
        op[1ull << 16] = fmaxf(v.y, 0.f);
        op[2ull << 16] = fmaxf(v.z, 0.f);
        op[3ull << 16] = fmaxf(v.w, 0.f);
    }
}

extern "C" void kernel_launch(void* const* d_in, const int* in_sizes, int n_in,
                              void* d_out, int out_size, void* d_ws, size_t ws_size,
                              hipStream_t stream) {
    const float* x1   = (const float*)d_in[0];
    const float* x2   = (const float*)d_in[1];
    const float* up_w = (const float*)d_in[2];
    const float* up_b = (const float*)d_in[3];
    const float* w1   = (const float*)d_in[4];
    const float* b1   = (const float*)d_in[5];
    const float* w2   = (const float*)d_in[6];
    const float* b2   = (const float*)d_in[7];
    const float* w3   = (const float*)d_in[8];
    const float* b3   = (const float*)d_in[9];
    u16* ws  = (u16*)d_ws;
    float* out = (float*)d_out;

    setup<<<1652, 256, 0, stream>>>(w1, w2, w3, up_w, x1, x2, ws);
    xc_up_mfma<<<512, 256, 0, stream>>>(ws + X1T_OFF, ws + UPWP_OFF, up_b, ws + XCB_OFF);
    conv1_mfma<<<1024, 256, 0, stream>>>(ws + XCB_OFF, ws + W1P_OFF, b1, ws + Y1B_OFF);
    conv2_mfma<<<1024, 256, 0, stream>>>(ws + Y1B_OFF, ws + XCB_OFF, ws + W2P_OFF,
                                         ws + W3P_OFF, b2, b3, out);
}

// Round 14
// 163.522 us; speedup vs baseline: 1.4220x; 1.4220x over previous
//
#include <hip/hip_runtime.h>

typedef unsigned short u16;
typedef __attribute__((ext_vector_type(8))) short short8;   // 8 bf16 (guide-verified MFMA frag type)
typedef __attribute__((ext_vector_type(4))) float f32x4;

// Workspace layout (u16 element offsets). Total 13,390,848 u16 = 26.8 MB.
#define XCB_OFF  0          // xc  channels-last bf16 [2][16^4][64] = 8,388,608
#define Y1B_OFF  8388608    // Y1  channels-last bf16 [2][16^4][32] = 4,194,304
#define W1P_OFF  12582912   // w1 prepacked [tap81][chunk2][half2][lane64][8] = 165,888
#define W2P_OFF  12748800   // w2 prepacked [tap81][half2][lane64][8]         =  82,944
#define W3P_OFF  12831744   // w3 prepacked [chunk2][half2][lane64][8]        =   2,048
#define UPWP_OFF 12833792   // up_w prepacked [tap16][chunk2][half2][lane64][8] = 32,768
#define X1T_OFF  12866560   // x1 channels-last bf16 [2][4096][64]            = 524,288

__device__ __forceinline__ u16 f2bf(float v) {   // RNE fp32 -> bf16 bits
    unsigned u = __builtin_bit_cast(unsigned, v);
    u += 0x7FFFu + ((u >> 16) & 1u);
    return (u16)(u >> 16);
}

__device__ __forceinline__ f32x4 MFMA(short8 a, short8 b, f32x4 c) {
    return __builtin_amdgcn_mfma_f32_16x16x32_bf16(a, b, c, 0, 0, 0);
}

// bid decode for conv kernels: grid 1024 = [b2][tsub2][d16][hB2][xcd8],
// xcd = bid&7 pinned to a t-pair (L2 locality). Each block = 8 h-rows.
__device__ __forceinline__ void decode_bid(int bid, int& b, int& t, int& d, int& h0) {
    int xcd = bid & 7, loc = bid >> 3;
    int hB = loc & 1;
    d = (loc >> 1) & 15;
    int tsub = (loc >> 5) & 1;
    b = loc >> 6;
    t = xcd * 2 + tsub;
    h0 = hB * 8;
}

// ---------------------------------------------------------------------------
// setup: fused (prepack weights | xc_copy | x1_tr) — all independent writes,
// branch by block range.
// ---------------------------------------------------------------------------
__global__ __launch_bounds__(256) void setup(const float* __restrict__ w1,
                                             const float* __restrict__ w2,
                                             const float* __restrict__ w3,
                                             const float* __restrict__ upw,
                                             const float* __restrict__ x1,
                                             const float* __restrict__ x2,
                                             u16* __restrict__ ws) {
    __shared__ u16 lds[256 * 66];
    int bid = blockIdx.x;
    int tid = threadIdx.x;
    if (bid < 1108) {
        // ---- prepack into MFMA A-frag order: a[lane][j] = A[m=lane&15][k=(lane>>4)*8+j]
        int idx = bid * 256 + tid;
        if (idx < 165888) {
            int j = idx & 7, lane = (idx >> 3) & 63, rest = idx >> 9;
            int half = rest & 1, chunk = (rest >> 1) & 1, tap = rest >> 2;
            int co = half * 16 + (lane & 15), ci = chunk * 32 + (lane >> 4) * 8 + j;
            ws[W1P_OFF + idx] = f2bf(w1[(co * 64 + ci) * 81 + tap]);
        } else if (idx < 165888 + 82944) {
            int i2 = idx - 165888;
            int j = i2 & 7, lane = (i2 >> 3) & 63, rest = i2 >> 9;
            int half = rest & 1, tap = rest >> 1;
            int co = half * 16 + (lane & 15), ci = (lane >> 4) * 8 + j;
            ws[W2P_OFF + i2] = f2bf(w2[(co * 32 + ci) * 81 + tap]);
        } else if (idx < 165888 + 82944 + 2048) {
            int i3 = idx - (165888 + 82944);
            int j = i3 & 7, lane = (i3 >> 3) & 63, rest = i3 >> 9;   // chunk*2+half
            int half = rest & 1, chunk = rest >> 1;
            int co = half * 16 + (lane & 15), ci = chunk * 32 + (lane >> 4) * 8 + j;
            ws[W3P_OFF + i3] = f2bf(w3[co * 64 + ci]);
        } else if (idx < 250880 + 32768) {
            int i4 = idx - 250880;                        // [tap][chunk][half][lane][8]
            int j = i4 & 7, lane = (i4 >> 3) & 63, rest = i4 >> 9;
            int half = rest & 1, chunk = (rest >> 1) & 1, tap = rest >> 2;
            int co = half * 16 + (lane & 15), ci = chunk * 32 + (lane >> 4) * 8 + j;
            ws[UPWP_OFF + i4] = f2bf(upw[(ci * 32 + co) * 16 + tap]);   // [Cin][Cout][taps]
        }
    } else if (bid < 1620) {
        // ---- xc_copy: x2 -> xcb channels 0..31 via padded-LDS transpose
        int lb = bid - 1108;
        int b = lb >> 8;
        int pos_base = (lb & 255) * 256;
        u16* xcb = ws + XCB_OFF;
        #pragma unroll
        for (int c = 0; c < 32; ++c) {
            lds[tid * 40 + c] = f2bf(x2[((b * 32 + c) << 16) + pos_base + tid]);
        }
        __syncthreads();
        #pragma unroll
        for (int k = 0; k < 4; ++k) {
            int f = k * 256 + tid;
            int u = f & 3, pos = f >> 2;
            uint4 v = *(const uint4*)(lds + pos * 40 + u * 8);
            *(uint4*)(xcb + (size_t)((b << 16) + pos_base + pos) * 64 + u * 8) = v;
        }
    } else {
        // ---- x1_tr: x1 -> x1t channels-last bf16 via padded-LDS transpose
        int lb = bid - 1620;                 // 32 blocks
        int b = lb >> 4;
        int pos_base = (lb & 15) * 256;
        u16* x1t = ws + X1T_OFF;
        #pragma unroll
        for (int c = 0; c < 64; ++c) {
            lds[tid * 66 + c] = f2bf(x1[((b * 64 + c) << 12) + pos_base + tid]);
        }
        __syncthreads();
        #pragma unroll
        for (int k = 0; k < 64; ++k) {
            int f = k * 256 + tid;
            int ci = f & 63, pos = f >> 6;
            x1t[(size_t)((b << 12) + pos_base + pos) * 64 + ci] = lds[pos * 66 + ci];
        }
    }
}

// ---------------------------------------------------------------------------
// xc_up_mfma: tconv4d(k2,s2) as 32 per-(b,tap) GEMMs [4096 ipos x 32 co, K=64].
// ---------------------------------------------------------------------------
__global__ __launch_bounds__(256) void xc_up_mfma(const u16* __restrict__ x1t,
                                                  const u16* __restrict__ upwp,
                                                  const float* __restrict__ up_b,
                                                  u16* __restrict__ xcb) {
    int tid = threadIdx.x;
    int wv = tid >> 6, lane = tid & 63;
    int q = lane >> 4, m = lane & 15;
    int wid = blockIdx.x * 4 + wv;               // [b2][tap16][j64]
    int j = wid & 63, tap = (wid >> 6) & 15, b = wid >> 10;

    f32x4 acc[4][2];
    {
        float4 bi0 = ((const float4*)up_b)[q];       // co = q*4+r
        float4 bi1 = ((const float4*)up_b)[4 + q];   // co = 16+q*4+r
        #pragma unroll
        for (int g = 0; g < 4; ++g) {
            acc[g][0] = (f32x4){bi0.x, bi0.y, bi0.z, bi0.w};
            acc[g][1] = (f32x4){bi1.x, bi1.y, bi1.z, bi1.w};
        }
    }

    const short8* wv8 = (const short8*)upwp;
    const u16* xb = x1t + (size_t)((b << 12) + (j << 6) + m) * 64;   // + (g*16)*64
    #pragma unroll
    for (int chunk = 0; chunk < 2; ++chunk) {
        short8 a0 = wv8[((tap * 2 + chunk) * 2 + 0) * 64 + lane];
        short8 a1 = wv8[((tap * 2 + chunk) * 2 + 1) * 64 + lane];
        #pragma unroll
        for (int g = 0; g < 4; ++g) {
            short8 bf = *(const short8*)(xb + (size_t)(g * 16) * 64 + chunk * 32 + q * 8);
            acc[g][0] = MFMA(a0, bf, acc[g][0]);
            acc[g][1] = MFMA(a1, bf, acc[g][1]);
        }
    }

    // epilogue: C/D col = ipos-local (lane&15), row = co-in-half = q*4+r.
    int it = j >> 3, id = j & 7;
    int pt = tap >> 3, pd = (tap >> 2) & 1, ph = (tap >> 1) & 1, pw = tap & 1;
    int oT = 2 * it + pt, oD = 2 * id + pd, oW = 2 * (m & 7) + pw;
    #pragma unroll
    for (int g = 0; g < 4; ++g) {
        int ih = g * 2 + (m >> 3);
        int opos = oT * 4096 + oD * 256 + (2 * ih + ph) * 16 + oW;
        u16* op = xcb + (size_t)((b << 16) + opos) * 64 + 32 + q * 4;
        #pragma unroll
        for (int half = 0; half < 2; ++half) {
            f32x4 v = acc[g][half];
            uint2 o;
            o.x = (unsigned)f2bf(v.x) | ((unsigned)f2bf(v.y) << 16);
            o.y = (unsigned)f2bf(v.z) | ((unsigned)f2bf(v.w) << 16);
            *(uint2*)(op + half * 16) = o;
        }
    }
}

// ---------------------------------------------------------------------------
// conv1: 3^4 conv, Cin=64 -> Cout=32, pad 1, +bias +ReLU -> Y1 (channels-last
// bf16). Block = 4 waves = (ci-chunk c) x (rowgroup rg), 8 h-rows x 32 co,
// grid 1024. LDS-staged planes + reg-prefetch pipeline (r12) + PLANE-ORDER
// ROTATION per block: co-resident blocks iterate (tt,dd) planes in rotated
// order so their stage phases interleave with neighbors' MFMA phases
// (r12 showed the blocks phase-lock -> CU-wide MFMA idle at every staging
// window). K-sum is commutative; fp32 accum -> order change is benign.
// ---------------------------------------------------------------------------
__global__ __launch_bounds__(256, 4) void conv1_mfma(const u16* __restrict__ xcb,
                                                     const u16* __restrict__ w1p,
                                                     const float* __restrict__ b1,
                                                     u16* __restrict__ y1b) {
    __shared__ u16 lds[11520];                   // 10*18*64 = 23 KB
    int tid = threadIdx.x;
    int lane = tid & 63, wv = tid >> 6;
    int q = lane >> 4, m = lane & 15;
    int c = wv & 1, rg = wv >> 1;                // ci-chunk, rowgroup
    int b, t, d, h0;
    decode_bid(blockIdx.x, b, t, d, h0);
    int rot = (blockIdx.x * 5) % 9;              // per-block plane rotation

    // per-thread staging descriptors (ktd-invariant): 6 x 16B units
    int lofs[6], gofs[6];
    bool st[6], inr[6];
    #pragma unroll
    for (int k = 0; k < 6; ++k) {
        int ui = tid + k * 256;
        int u = ui & 7, p = (ui >> 3) % 18, hh = ui / 144;
        int gh = h0 - 1 + hh, gw = p - 1;
        st[k] = ui < 1440;
        inr[k] = st[k] && ((unsigned)gh < 16u) && ((unsigned)gw < 16u);
        gofs[k] = (gh * 16 + gw) * 64 + u * 8;
        lofs[k] = hh * 1152 + p * 64 + ((u ^ (p & 7)) * 8);
    }

    f32x4 acc[4][2];                             // [row i][co half]
    if (c == 0) {
        float4 bi0 = ((const float4*)b1)[q];
        float4 bi1 = ((const float4*)b1)[4 + q];
        #pragma unroll
        for (int i = 0; i < 4; ++i) {
            acc[i][0] = (f32x4){bi0.x, bi0.y, bi0.z, bi0.w};
            acc[i][1] = (f32x4){bi1.x, bi1.y, bi1.z, bi1.w};
        }
    } else {
        #pragma unroll
        for (int i = 0; i < 4; ++i) {
            acc[i][0] = (f32x4){0.f, 0.f, 0.f, 0.f};
            acc[i][1] = (f32x4){0.f, 0.f, 0.f, 0.f};
        }
    }
    const short8* w1v = (const short8*)w1p;

    uint4 rP[6];
    auto load_plane = [&](int ktd) {
        int kt = ktd / 3, kd = ktd - kt * 3;
        int tt = t + kt - 1, dd = d + kd - 1;
        bool pv = ((unsigned)tt < 16u) && ((unsigned)dd < 16u);
        const u16* src = xcb + (size_t)(((b * 16 + tt) * 16 + dd)) * 16384;
        #pragma unroll
        for (int k = 0; k < 6; ++k) {
            uint4 v = {0, 0, 0, 0};
            if (pv && inr[k]) v = *(const uint4*)(src + gofs[k]);
            rP[k] = v;
        }
    };
    auto write_plane = [&]() {
        #pragma unroll
        for (int k = 0; k < 6; ++k)
            if (st[k]) *(uint4*)(lds + lofs[k]) = rP[k];
    };

    load_plane(rot);
    for (int s = 0; s < 9; ++s) {
        int ktd = rot + s; if (ktd >= 9) ktd -= 9;
        __syncthreads();                          // all waves done reading old plane
        write_plane();                            // regs arrived during prev MFMA phase
        if (s < 8) {
            int nk = ktd + 1; if (nk >= 9) nk -= 9;
            load_plane(nk);                       // prefetch next plane NOW
        }
        __syncthreads();                          // new plane visible
        // ---- MFMA phase on plane ktd ----
        #pragma unroll
        for (int kw = 0; kw < 3; ++kw) {
            int p = kw + m, pm = p & 7;
            int bo = p * 64 + ((((c << 2) | q) ^ pm) << 3);
            short8 R[6];
            #pragma unroll
            for (int r = 0; r < 6; ++r)           // halo rows rg*4 .. rg*4+5
                R[r] = *(const short8*)(lds + (rg * 4 + r) * 1152 + bo);
            #pragma unroll
            for (int kh = 0; kh < 3; ++kh) {
                int tap = (ktd * 3 + kh) * 3 + kw;
                short8 a0 = w1v[((tap * 2 + c) * 2 + 0) * 64 + lane];
                short8 a1 = w1v[((tap * 2 + c) * 2 + 1) * 64 + lane];
                #pragma unroll
                for (int i = 0; i < 4; ++i) {
                    acc[i][0] = MFMA(a0, R[i + kh], acc[i][0]);
                    acc[i][1] = MFMA(a1, R[i + kh], acc[i][1]);
                }
            }
        }
    }

    // ---- K-reduction: chunk1 partials -> chunk0, via LDS (16 KB overlay) ----
    __syncthreads();
    f32x4* buf = (f32x4*)lds;
    if (c == 1) {
        #pragma unroll
        for (int i = 0; i < 4; ++i)
            #pragma unroll
            for (int half = 0; half < 2; ++half)
                buf[((rg * 4 + i) * 2 + half) * 64 + lane] = acc[i][half];
    }
    __syncthreads();
    if (c == 0) {
        int obase = ((b * 16 + t) * 16 + d) * 256 + (h0 + rg * 4) * 16 + m;
        #pragma unroll
        for (int i = 0; i < 4; ++i) {
            int pos = obase + i * 16;
            #pragma unroll
            for (int half = 0; half < 2; ++half) {
                f32x4 v = acc[i][half];
                f32x4 w = buf[((rg * 4 + i) * 2 + half) * 64 + lane];
                v.x += w.x; v.y += w.y; v.z += w.z; v.w += w.w;
                unsigned r0 = f2bf(fmaxf(v.x, 0.f)), r1 = f2bf(fmaxf(v.y, 0.f));
                unsigned r2 = f2bf(fmaxf(v.z, 0.f)), r3 = f2bf(fmaxf(v.w, 0.f));
                uint2 o;
                o.x = r0 | (r1 << 16);
                o.y = r2 | (r3 << 16);
                *(uint2*)(y1b + (size_t)pos * 32 + half * 16 + q * 4) = o;
            }
        }
    }
}

// ---------------------------------------------------------------------------
// conv2: 3^4 conv Cin=32->Cout=32 on Y1 + fused 1x1 skip (xc, Cin=64) + biases
// + final ReLU -> fp32 output [b][co][t][d][h][w]. Block = 4 waves =
// (co-half hf) x (rowgroup rg), grid 1024. Same pipeline + rotation.
// ---------------------------------------------------------------------------
__global__ __launch_bounds__(256, 4) void conv2_mfma(const u16* __restrict__ y1b,
                                                     const u16* __restrict__ xcb,
                                                     const u16* __restrict__ w2p,
                                                     const u16* __restrict__ w3p,
                                                     const float* __restrict__ b2,
                                                     const float* __restrict__ b3,
                                                     float* __restrict__ out) {
    __shared__ u16 lds[5760];                    // 10*18*32 = 11.5 KB
    int tid = threadIdx.x;
    int lane = tid & 63, wv = tid >> 6;
    int q = lane >> 4, m = lane & 15;
    int hf = wv & 1, rg = wv >> 1;               // co-half, rowgroup
    int b, t, d, h0;
    decode_bid(blockIdx.x, b, t, d, h0);
    int rot = (blockIdx.x * 5) % 9;

    int lofs[3], gofs[3];
    bool st[3], inr[3];
    #pragma unroll
    for (int k = 0; k < 3; ++k) {
        int ui = tid + k * 256;
        int u = ui & 3, p = (ui >> 2) % 18, hh = ui / 72;
        int gh = h0 - 1 + hh, gw = p - 1;
        st[k] = ui < 720;
        inr[k] = st[k] && ((unsigned)gh < 16u) && ((unsigned)gw < 16u);
        gofs[k] = (gh * 16 + gw) * 32 + u * 8;
        lofs[k] = hh * 576 + p * 32 + ((u ^ (p & 3)) * 8);
    }

    f32x4 acc[4];                                // [row i], this wave's co-half
    {
        float4 p0 = ((const float4*)b2)[hf * 4 + q];
        float4 s0 = ((const float4*)b3)[hf * 4 + q];
        #pragma unroll
        for (int i = 0; i < 4; ++i)
            acc[i] = (f32x4){p0.x + s0.x, p0.y + s0.y, p0.z + s0.z, p0.w + s0.w};
    }
    const short8* w2v = (const short8*)w2p;

    uint4 rP[3];
    auto load_plane = [&](int ktd) {
        int kt = ktd / 3, kd = ktd - kt * 3;
        int tt = t + kt - 1, dd = d + kd - 1;
        bool pv = ((unsigned)tt < 16u) && ((unsigned)dd < 16u);
        const u16* src = y1b + (size_t)(((b * 16 + tt) * 16 + dd)) * 8192;
        #pragma unroll
        for (int k = 0; k < 3; ++k) {
            uint4 v = {0, 0, 0, 0};
            if (pv && inr[k]) v = *(const uint4*)(src + gofs[k]);
            rP[k] = v;
        }
    };
    auto write_plane = [&]() {
        #pragma unroll
        for (int k = 0; k < 3; ++k)
            if (st[k]) *(uint4*)(lds + lofs[k]) = rP[k];
    };

    load_plane(rot);
    for (int s = 0; s < 9; ++s) {
        int ktd = rot + s; if (ktd >= 9) ktd -= 9;
        __syncthreads();
        write_plane();
        if (s < 8) {
            int nk = ktd + 1; if (nk >= 9) nk -= 9;
            load_plane(nk);
        }
        __syncthreads();
        #pragma unroll
        for (int kw = 0; kw < 3; ++kw) {
            int p = kw + m, pm = p & 3;
            int bo = p * 32 + ((q ^ pm) << 3);
            short8 R[6];
            #pragma unroll
            for (int r = 0; r < 6; ++r)
                R[r] = *(const short8*)(lds + (rg * 4 + r) * 576 + bo);
            #pragma unroll
            for (int kh = 0; kh < 3; ++kh) {
                int tap = (ktd * 3 + kh) * 3 + kw;
                short8 a = w2v[(tap * 2 + hf) * 64 + lane];
                #pragma unroll
                for (int i = 0; i < 4; ++i) {
                    acc[i] = MFMA(a, R[i + kh], acc[i]);
                }
            }
        }
    }

    // ---- fused 1x1 skip conv from xc (Cin=64, 2 chunks), B direct from global
    const short8* w3v = (const short8*)w3p;
    int lpos0 = (t * 16 + d) * 256 + (h0 + rg * 4) * 16 + m;   // batch-local pos
    int gpos0 = (b << 16) + lpos0;                             // global pos (ws arrays)
    #pragma unroll
    for (int chunk = 0; chunk < 2; ++chunk) {
        short8 a = w3v[(chunk * 2 + hf) * 64 + lane];
        #pragma unroll
        for (int i = 0; i < 4; ++i) {
            short8 bf = *(const short8*)(xcb + (size_t)(gpos0 + i * 16) * 64 + ((chunk << 2) | q) * 8);
            acc[i] = MFMA(a, bf, acc[i]);
        }
    }

    // ---- epilogue: ReLU, fp32 store to [b][co][local_pos] ----
    #pragma unroll
    for (int i = 0; i < 4; ++i) {
        int lpos = lpos0 + i * 16;
        f32x4 v = acc[i];
        int co = hf * 16 + q * 4;
        float* op = out + (((size_t)(b * 32 + co)) << 16) + lpos;
        op[0ull << 16] = fmaxf(v.x, 0.f);
        op[1ull << 16] = fmaxf(v.y, 0.f);
        op[2ull << 16] = fmaxf(v.z, 0.f);
        op[3ull << 16] = fmaxf(v.w, 0.f);
    }
}

extern "C" void kernel_launch(void* const* d_in, const int* in_sizes, int n_in,
                              void* d_out, int out_size, void* d_ws, size_t ws_size,
                              hipStream_t stream) {
    const float* x1   = (const float*)d_in[0];
    const float* x2   = (const float*)d_in[1];
    const float* up_w = (const float*)d_in[2];
    const float* up_b = (const float*)d_in[3];
    const float* w1   = (const float*)d_in[4];
    const float* b1   = (const float*)d_in[5];
    const float* w2   = (const float*)d_in[6];
    const float* b2   = (const float*)d_in[7];
    const float* w3   = (const float*)d_in[8];
    const float* b3   = (const float*)d_in[9];
    u16* ws  = (u16*)d_ws;
    float* out = (float*)d_out;

    setup<<<1652, 256, 0, stream>>>(w1, w2, w3, up_w, x1, x2, ws);
    xc_up_mfma<<<512, 256, 0, stream>>>(ws + X1T_OFF, ws + UPWP_OFF, up_b, ws + XCB_OFF);
    conv1_mfma<<<1024, 256, 0, stream>>>(ws + XCB_OFF, ws + W1P_OFF, b1, ws + Y1B_OFF);
    conv2_mfma<<<1024, 256, 0, stream>>>(ws + Y1B_OFF, ws + XCB_OFF, ws + W2P_OFF,
                                         ws + W3P_OFF, b2, b3, out);
}